// Round 3
// baseline (110.754 us; speedup 1.0000x reference)
//
#include <hip/hip_runtime.h>
#include <stdint.h>

typedef float f32x4 __attribute__((ext_vector_type(4)));
typedef short short8 __attribute__((ext_vector_type(8)));
typedef short short4v __attribute__((ext_vector_type(4)));

#define N_SPATIAL 65536   // 256*256
#define DIM 256
#define GROUPS 32
#define HIDDEN 128

__device__ __forceinline__ float b2f(uint16_t u) {
  union { uint32_t u; float f; } v; v.u = ((uint32_t)u) << 16; return v.f;
}
__device__ __forceinline__ uint16_t f2b(float f) {
  union { float f; uint32_t u; } v; v.f = f;
  uint32_t r = (v.u + 0x7FFFu + ((v.u >> 16) & 1u)) >> 16;
  return (uint16_t)r;
}

// ---------------------------------------------------------------------------
// K1: transpose x (c,n) fp32 -> xT (n,c) bf16, plus GroupNorm partial stats.
// grid 1024 (64-n tiles), block 256.
__global__ __launch_bounds__(256) void k1_transpose_stats(
    const float* __restrict__ x, uint16_t* __restrict__ xT, float* __restrict__ gnp) {
  __shared__ uint16_t xs[64][264];   // [n][c] padded stride 264
  const int t = threadIdx.x;
  const int n0 = blockIdx.x * 64;
  const int c_l = (t >> 2) & 15;
  const int nq  = (t & 3) + 4 * (t >> 6);
  for (int p = 0; p < 16; ++p) {
    int c = 16 * p + c_l;
    float4 v = *(const float4*)(x + (size_t)c * N_SPATIAL + n0 + nq * 4);
    int nn = nq * 4;
    xs[nn + 0][c] = f2b(v.x); xs[nn + 1][c] = f2b(v.y);
    xs[nn + 2][c] = f2b(v.z); xs[nn + 3][c] = f2b(v.w);
  }
  __syncthreads();
  {
    int g = t >> 3; int c = g * 8 + (t & 7);
    float s = 0.f, ss = 0.f;
    for (int n = 0; n < 64; ++n) { float f = b2f(xs[n][c]); s += f; ss += f * f; }
    s  += __shfl_xor(s, 1, 64);  ss += __shfl_xor(ss, 1, 64);
    s  += __shfl_xor(s, 2, 64);  ss += __shfl_xor(ss, 2, 64);
    s  += __shfl_xor(s, 4, 64);  ss += __shfl_xor(ss, 4, 64);
    if ((t & 7) == 0) {
      gnp[((size_t)blockIdx.x * 32 + g) * 2 + 0] = s;
      gnp[((size_t)blockIdx.x * 32 + g) * 2 + 1] = ss;
    }
  }
  for (int p = 0; p < 8; ++p) {
    int j = t + 256 * p; int n = j >> 5; int c16 = j & 31;
    f32x4 val = *(const f32x4*)((const char*)&xs[0][0] + n * 528 + c16 * 16);
    *(f32x4*)((char*)xT + ((size_t)(n0 + n)) * 512 + c16 * 16) = val;
  }
}

// ---------------------------------------------------------------------------
// K2: reduce stats partials -> per-channel a,b.  grid 32, block 256.
__global__ __launch_bounds__(256) void k2_stats_final(
    const float* __restrict__ gnp, const float* __restrict__ gnw,
    const float* __restrict__ gnb, float* __restrict__ ab) {
  __shared__ float red[4][2];
  const int g = blockIdx.x; const int t = threadIdx.x;
  float s = 0.f, ss = 0.f;
  for (int c = t; c < 1024; c += 256) {
    s  += gnp[((size_t)c * 32 + g) * 2 + 0];
    ss += gnp[((size_t)c * 32 + g) * 2 + 1];
  }
  for (int m = 32; m >= 1; m >>= 1) { s += __shfl_xor(s, m, 64); ss += __shfl_xor(ss, m, 64); }
  if ((t & 63) == 0) { red[t >> 6][0] = s; red[t >> 6][1] = ss; }
  __syncthreads();
  if (t == 0) {
    float S  = red[0][0] + red[1][0] + red[2][0] + red[3][0];
    float SS = red[0][1] + red[1][1] + red[2][1] + red[3][1];
    const float invN = 1.0f / 524288.0f;
    float mean = S * invN;
    float var  = SS * invN - mean * mean;
    float rs   = rsqrtf(var + 1e-5f);
    for (int i = 0; i < 8; ++i) {
      int c = g * 8 + i;
      float aa = gnw[c] * rs;
      ab[c] = aa;
      ab[256 + c] = gnb[c] - mean * aa;
    }
  }
}

// ---------------------------------------------------------------------------
// K2b: fold norm into qkv weights: W'[o][c]=W*a (bf16), bias'[o]=qb[o]+sum W*b.
// grid 384, block 64.
__global__ __launch_bounds__(64) void k2b_fold_w(
    const float* __restrict__ qw, const float* __restrict__ qb,
    const float* __restrict__ ab, uint16_t* __restrict__ wp, float* __restrict__ biasp) {
  const int o = blockIdx.x; const int l = threadIdx.x;
  float4 w  = *(const float4*)(qw + (size_t)o * 256 + l * 4);
  float4 av = *(const float4*)(ab + l * 4);
  float4 bv = *(const float4*)(ab + 256 + l * 4);
  short4v pk;
  pk[0] = (short)f2b(w.x * av.x); pk[1] = (short)f2b(w.y * av.y);
  pk[2] = (short)f2b(w.z * av.z); pk[3] = (short)f2b(w.w * av.w);
  *(short4v*)(wp + (size_t)o * 256 + l * 4) = pk;
  float part = w.x * bv.x + w.y * bv.y + w.z * bv.z + w.w * bv.w;
  for (int m = 32; m >= 1; m >>= 1) part += __shfl_xor(part, m, 64);
  if (l == 0) biasp[o] = qb[o] + part;
}

// ---------------------------------------------------------------------------
// K3f: fused qkv GEMM + in-block linear-attention context.
// Per block: n-tile of 128 pixels, all 384 output rows (mt = q,k,v sequential).
//  mt=0: q -> qT[n][128] bf16 (transposed via LDS, coalesced)
//  mt=1: k -> exp(k) bf16 -> ekbuf (LDS, persists)
//  mt=2: v -> bf16 -> vbuf (LDS)
// Then per-head context via MFMA: ctx[d][e] = sum_n ek[d][n] v[e][n], den[d].
// grid 512, block 256 (4 waves; wave = head in context phase). LDS 64KB.
__global__ __launch_bounds__(256) void k3_fused(
    const uint16_t* __restrict__ xT, const uint16_t* __restrict__ wp,
    const float* __restrict__ biasp, uint16_t* __restrict__ qT,
    float* __restrict__ part) {
  __shared__ __align__(16) char smem[65536];  // [0,16K) A-stage, [16K,32K) B-stage / qbuf / vbuf, [32K,64K) ekbuf
  const int t = threadIdx.x;
  const int n0 = blockIdx.x * 128;
  const int l = t & 63, wid = t >> 6, wr = wid >> 1, wc = wid & 1;
  const int lrow = l & 15, lk = l >> 4, lr7 = lrow & 7;
  const int srow = t >> 3, sch = t & 7;
  const int chs = sch ^ (srow & 7);

  for (int mt = 0; mt < 3; ++mt) {
    const int o0 = mt * 128;
    f32x4 acc[4][4] = {};
    for (int ks = 0; ks < 4; ++ks) {
      const int k0 = ks * 64;
      __syncthreads();
      #pragma unroll
      for (int p = 0; p < 4; ++p) {
        int row = srow + 32 * p;
        f32x4 va = *(const f32x4*)((const char*)wp + (size_t)(o0 + row) * 512 + k0 * 2 + sch * 16);
        *(f32x4*)(&smem[row * 128 + chs * 16]) = va;
        f32x4 vb = *(const f32x4*)((const char*)xT + (size_t)(n0 + row) * 512 + k0 * 2 + sch * 16);
        *(f32x4*)(&smem[16384 + row * 128 + chs * 16]) = vb;
      }
      __syncthreads();
      #pragma unroll
      for (int kk = 0; kk < 2; ++kk) {
        short8 a[4], b[4];
        #pragma unroll
        for (int m = 0; m < 4; ++m) {
          int row = wr * 64 + m * 16 + lrow;
          a[m] = *(const short8*)(&smem[row * 128 + (((kk * 4 + lk) ^ lr7) << 4)]);
        }
        #pragma unroll
        for (int n = 0; n < 4; ++n) {
          int row = wc * 64 + n * 16 + lrow;
          b[n] = *(const short8*)(&smem[16384 + row * 128 + (((kk * 4 + lk) ^ lr7) << 4)]);
        }
        #pragma unroll
        for (int m = 0; m < 4; ++m)
          #pragma unroll
          for (int n = 0; n < 4; ++n)
            acc[m][n] = __builtin_amdgcn_mfma_f32_16x16x32_bf16(a[m], b[n], acc[m][n], 0, 0, 0);
      }
    }
    __syncthreads();   // all LDS reads of staging done before epilogue overwrites

    if (mt == 0) {
      // q: add bias, pack bf16, transpose via LDS [0,32K), coalesced store to qT
      #pragma unroll
      for (int m = 0; m < 4; ++m) {
        int ob = wr * 64 + m * 16 + lk * 4;
        float b0 = biasp[ob + 0], b1 = biasp[ob + 1], b2 = biasp[ob + 2], b3 = biasp[ob + 3];
        #pragma unroll
        for (int n = 0; n < 4; ++n) {
          int nn = wc * 64 + n * 16 + lrow;
          short4v pk;
          pk[0] = (short)f2b(acc[m][n][0] + b0);
          pk[1] = (short)f2b(acc[m][n][1] + b1);
          pk[2] = (short)f2b(acc[m][n][2] + b2);
          pk[3] = (short)f2b(acc[m][n][3] + b3);
          *(short4v*)(&smem[nn * 256 + ((ob * 2) ^ ((nn & 7) << 4))]) = pk;
        }
      }
      __syncthreads();
      #pragma unroll
      for (int p = 0; p < 8; ++p) {
        int j = t + 256 * p; int n = j >> 4; int o8 = j & 15;
        f32x4 v = *(const f32x4*)(&smem[n * 256 + ((o8 * 16) ^ ((n & 7) << 4))]);
        *(f32x4*)((char*)qT + (size_t)(n0 + n) * 256 + o8 * 16) = v;
      }
    } else if (mt == 1) {
      // k: add bias, exp (fp32), pack bf16 -> ekbuf [32K,64K), swizzled [row d][n]
      #pragma unroll
      for (int m = 0; m < 4; ++m) {
        int ob = 128 + wr * 64 + m * 16 + lk * 4;
        float b0 = biasp[ob + 0], b1 = biasp[ob + 1], b2 = biasp[ob + 2], b3 = biasp[ob + 3];
        #pragma unroll
        for (int n = 0; n < 4; ++n) {
          int nn = wc * 64 + n * 16 + lrow;
          int rbase = wr * 64 + m * 16 + lk * 4;
          float e0 = __expf(acc[m][n][0] + b0);
          float e1 = __expf(acc[m][n][1] + b1);
          float e2 = __expf(acc[m][n][2] + b2);
          float e3 = __expf(acc[m][n][3] + b3);
          #pragma unroll
          for (int j = 0; j < 4; ++j) {
            int row = rbase + j;
            float ev = (j == 0) ? e0 : (j == 1) ? e1 : (j == 2) ? e2 : e3;
            *(uint16_t*)(&smem[32768 + row * 256 + ((((nn >> 3) ^ (row & 7)) << 4)) + (nn & 7) * 2]) = f2b(ev);
          }
        }
      }
    } else {
      // v: add bias, pack bf16 -> vbuf [0,32K), swizzled [row e][n]
      #pragma unroll
      for (int m = 0; m < 4; ++m) {
        int ob = 256 + wr * 64 + m * 16 + lk * 4;
        float b0 = biasp[ob + 0], b1 = biasp[ob + 1], b2 = biasp[ob + 2], b3 = biasp[ob + 3];
        #pragma unroll
        for (int n = 0; n < 4; ++n) {
          int nn = wc * 64 + n * 16 + lrow;
          int rbase = wr * 64 + m * 16 + lk * 4;
          float v0 = acc[m][n][0] + b0, v1 = acc[m][n][1] + b1;
          float v2 = acc[m][n][2] + b2, v3 = acc[m][n][3] + b3;
          #pragma unroll
          for (int j = 0; j < 4; ++j) {
            int row = rbase + j;
            float vv = (j == 0) ? v0 : (j == 1) ? v1 : (j == 2) ? v2 : v3;
            *(uint16_t*)(&smem[row * 256 + ((((nn >> 3) ^ (row & 7)) << 4)) + (nn & 7) * 2]) = f2b(vv);
          }
        }
      }
    }
  }
  __syncthreads();   // ek + v staged

  // context phase: wave = head. ctx[d][e] = sum_n ek[h*32+d][n] * v[h*32+e][n]
  {
    const int h = wid;
    f32x4 cacc[2][2] = {};
    #pragma unroll
    for (int kw = 0; kw < 4; ++kw) {
      short8 ae[2], be[2];
      #pragma unroll
      for (int mf = 0; mf < 2; ++mf) {
        int row = h * 32 + mf * 16 + lrow;
        ae[mf] = *(const short8*)(&smem[32768 + row * 256 + ((((kw * 4 + lk) ^ (row & 7)) << 4))]);
      }
      #pragma unroll
      for (int nf = 0; nf < 2; ++nf) {
        int row = h * 32 + nf * 16 + lrow;
        be[nf] = *(const short8*)(&smem[row * 256 + ((((kw * 4 + lk) ^ (row & 7)) << 4))]);
      }
      #pragma unroll
      for (int mf = 0; mf < 2; ++mf)
        #pragma unroll
        for (int nf = 0; nf < 2; ++nf)
          cacc[mf][nf] = __builtin_amdgcn_mfma_f32_16x16x32_bf16(ae[mf], be[nf], cacc[mf][nf], 0, 0, 0);
    }
    // denominator: den[d] = sum_n ek[h*32+d][n]
    float den = 0.f;
    {
      int d = l & 31; int half = l >> 5;
      int row = h * 32 + d;
      #pragma unroll
      for (int c8 = 0; c8 < 8; ++c8) {
        int c = half * 8 + c8;
        short8 v8 = *(const short8*)(&smem[32768 + row * 256 + (((c ^ (row & 7)) << 4))]);
        #pragma unroll
        for (int i = 0; i < 8; ++i) den += b2f(((const uint16_t*)&v8)[i]);
      }
      den += __shfl_xor(den, 32, 64);
    }
    float* pp = part + (size_t)blockIdx.x * 4224 + h * 1056;
    #pragma unroll
    for (int mf = 0; mf < 2; ++mf)
      #pragma unroll
      for (int nf = 0; nf < 2; ++nf)
        #pragma unroll
        for (int j = 0; j < 4; ++j) {
          int d = mf * 16 + lk * 4 + j, e = nf * 16 + lrow;
          pp[d * 32 + e] = cacc[mf][nf][j];
        }
    if (l < 32) pp[1024 + (l & 31)] = den;
  }
}

// ---------------------------------------------------------------------------
// K6: reduce context partials over 512 blocks.  grid 17, block 256.
__global__ __launch_bounds__(256) void k6_reduce(
    const float* __restrict__ part, float* __restrict__ ctxs) {
  int id = blockIdx.x * 256 + threadIdx.x;
  if (id >= 4224) return;
  const float* p = part + id;
  float s = 0.f;
  for (int c = 0; c < 512; ++c) s += p[(size_t)c * 4224];
  ctxs[id] = s;
}

// ---------------------------------------------------------------------------
// K6b: fold out_weight with normalized context -> M[o][h*32+d] bf16.
// grid 256, block 128.
__global__ __launch_bounds__(128) void k6b_fold(
    const float* __restrict__ ow, const float* __restrict__ ctxs, uint16_t* __restrict__ Mw) {
  const int o = blockIdx.x; const int t = threadIdx.x;
  const int h = t >> 5, d = t & 31;
  const float* cs = ctxs + h * 1056;
  float den = cs[1024 + d];
  float s = 0.f;
  for (int e = 0; e < 32; ++e) s += ow[(size_t)o * 128 + h * 32 + e] * cs[d * 32 + e];
  Mw[(size_t)o * 128 + t] = f2b(s / den);
}

// ---------------------------------------------------------------------------
// K7: out = M(256x128) @ q(128x65536) + out_bias.  Whole-K staged once;
// output staged through 64KB LDS for fully coalesced 512B-row f32x4 stores.
// grid 1024, block 256.
__global__ __launch_bounds__(256) void k7_out(
    const uint16_t* __restrict__ qT, const uint16_t* __restrict__ Mw,
    const float* __restrict__ obias, float* __restrict__ out) {
  __shared__ __align__(16) char smem[65536];
  const int t = threadIdx.x;
  const int mt = blockIdx.x & 1, nt = blockIdx.x >> 1;
  const int o0 = mt * 128, n0 = nt * 128;
  const int l = t & 63, wid = t >> 6, wr = wid >> 1, wc = wid & 1;
  const int lrow = l & 15, lk = l >> 4, lr7 = lrow & 7;

  // stage A (Mw rows o0..o0+128) at [0,32K), B (qT rows n0..) at [32K,64K)
  #pragma unroll
  for (int i = 0; i < 8; ++i) {
    int flat = t + 256 * i;            // 0..2047 chunks of 16B
    int row = flat >> 4, c = flat & 15;
    int cs = c ^ (row & 7);
    f32x4 va = *(const f32x4*)((const char*)Mw + (size_t)(o0 + row) * 256 + c * 16);
    *(f32x4*)(&smem[row * 256 + cs * 16]) = va;
    f32x4 vb = *(const f32x4*)((const char*)qT + (size_t)(n0 + row) * 256 + c * 16);
    *(f32x4*)(&smem[32768 + row * 256 + cs * 16]) = vb;
  }
  __syncthreads();

  f32x4 acc[4][4] = {};
  #pragma unroll
  for (int kw = 0; kw < 4; ++kw) {
    short8 a[4], b[4];
    #pragma unroll
    for (int m = 0; m < 4; ++m) {
      int row = wr * 64 + m * 16 + lrow;
      a[m] = *(const short8*)(&smem[row * 256 + (((kw * 4 + lk) ^ lr7) << 4)]);
    }
    #pragma unroll
    for (int n = 0; n < 4; ++n) {
      int row = wc * 64 + n * 16 + lrow;
      b[n] = *(const short8*)(&smem[32768 + row * 256 + (((kw * 4 + lk) ^ lr7) << 4)]);
    }
    #pragma unroll
    for (int m = 0; m < 4; ++m)
      #pragma unroll
      for (int n = 0; n < 4; ++n)
        acc[m][n] = __builtin_amdgcn_mfma_f32_16x16x32_bf16(a[m], b[n], acc[m][n], 0, 0, 0);
  }
  __syncthreads();

  // stage output tile (128o x 128n fp32, row stride 512B, 16B-chunk XOR swizzle)
  #pragma unroll
  for (int m = 0; m < 4; ++m) {
    int ob = o0 + wr * 64 + m * 16 + lk * 4;
    float b0 = obias[ob + 0], b1 = obias[ob + 1], b2 = obias[ob + 2], b3 = obias[ob + 3];
    #pragma unroll
    for (int n = 0; n < 4; ++n) {
      int col = wc * 64 + n * 16 + lrow;
      int rbase = wr * 64 + m * 16 + lk * 4;
      float v0 = acc[m][n][0] + b0, v1 = acc[m][n][1] + b1;
      float v2 = acc[m][n][2] + b2, v3 = acc[m][n][3] + b3;
      #pragma unroll
      for (int j = 0; j < 4; ++j) {
        int row = rbase + j;
        float vv = (j == 0) ? v0 : (j == 1) ? v1 : (j == 2) ? v2 : v3;
        *(float*)(&smem[row * 512 + ((((col >> 2) ^ (row & 7)) << 4)) + (col & 3) * 4]) = vv;
      }
    }
  }
  __syncthreads();
  #pragma unroll
  for (int i = 0; i < 16; ++i) {
    int flat = t + 256 * i;            // 0..4095 chunks of 16B
    int row = flat >> 5, c = flat & 31;
    f32x4 v = *(const f32x4*)(&smem[row * 512 + (((c ^ (row & 7)) << 4))]);
    *(f32x4*)(out + (size_t)(o0 + row) * N_SPATIAL + n0 + c * 4) = v;
  }
}

// ---------------------------------------------------------------------------
extern "C" void kernel_launch(void* const* d_in, const int* in_sizes, int n_in,
                              void* d_out, int out_size, void* d_ws, size_t ws_size,
                              hipStream_t stream) {
  const float* x   = (const float*)d_in[0];
  const float* gnw = (const float*)d_in[1];
  const float* gnb = (const float*)d_in[2];
  const float* qw  = (const float*)d_in[3];
  const float* qb  = (const float*)d_in[4];
  const float* ow  = (const float*)d_in[5];
  const float* ob  = (const float*)d_in[6];
  float* out = (float*)d_out;
  char* ws = (char*)d_ws;

  uint16_t* xT    = (uint16_t*)(ws + 0);          // 32 MB
  uint16_t* qT    = (uint16_t*)(ws + 33554432);   // 16 MB
  uint16_t* wp    = (uint16_t*)(ws + 50331648);   // 192 KB
  float*    biasp = (float*)   (ws + 50528256);   // 1.5 KB
  float*    ab    = (float*)   (ws + 50529792);   // 2 KB
  float*    gnp   = (float*)   (ws + 50531840);   // 256 KB
  float*    part  = (float*)   (ws + 50794496);   // 8.65 MB (512*4224*4)
  float*    ctxs  = (float*)   (ws + 59445248);   // 16.9 KB
  uint16_t* Mw    = (uint16_t*)(ws + 59462144);   // 64 KB

  k1_transpose_stats<<<dim3(1024), dim3(256), 0, stream>>>(x, xT, gnp);
  k2_stats_final<<<dim3(32), dim3(256), 0, stream>>>(gnp, gnw, gnb, ab);
  k2b_fold_w<<<dim3(384), dim3(64), 0, stream>>>(qw, qb, ab, wp, biasp);
  k3_fused<<<dim3(512), dim3(256), 0, stream>>>(xT, wp, biasp, qT, part);
  k6_reduce<<<dim3(17), dim3(256), 0, stream>>>(part, ctxs);
  k6b_fold<<<dim3(256), dim3(128), 0, stream>>>(ow, ctxs, Mw);
  k7_out<<<dim3(1024), dim3(256), 0, stream>>>(qT, Mw, ob, out);
}